// Round 1
// 381.382 us; speedup vs baseline: 1.0523x; 1.0523x over previous
//
#include <hip/hip_runtime.h>

#define M_DIM 4096
#define N_DIM 8192
#define K_DIM 2048
#define NGRP 16
#define GSZ 512
#define EPSV 1e-5f

#define NX (M_DIM * K_DIM)            // x elems  = 8388608
#define NW (N_DIM * K_DIM)            // W elems  = 16777216
#define NY ((size_t)M_DIM * N_DIM)    // y elems  = 33554432

typedef __attribute__((ext_vector_type(8))) short bf16x8;
typedef __attribute__((ext_vector_type(4))) float f32x4;
typedef __attribute__((ext_vector_type(8))) short shortx8;

__device__ __forceinline__ float b2f(short u) {
    union { unsigned u32; float f; } c;
    c.u32 = ((unsigned)(unsigned short)u) << 16;
    return c.f;
}

__device__ __forceinline__ short f2b(float f) {
    union { float f; unsigned u; } c; c.f = f;
    unsigned r = (c.u + 0x7fffu + ((c.u >> 16) & 1u)) >> 16;
    return (short)r;
}

// ---------------- fp32 -> bf16 bulk convert (x then W, contiguous dst) -------
__global__ __launch_bounds__(256) void convert_kernel(
    const float* __restrict__ x, const float* __restrict__ W,
    short* __restrict__ dst)
{
    const size_t base = ((size_t)blockIdx.x * 256 + threadIdx.x) * 32;
    const float* src = (base < NX) ? (x + base) : (W + (base - NX));
    f32x4 v[8];
#pragma unroll
    for (int c = 0; c < 8; ++c) v[c] = *(const f32x4*)(src + c * 4);
#pragma unroll
    for (int c = 0; c < 4; ++c) {
        shortx8 o;
#pragma unroll
        for (int j = 0; j < 4; ++j) {
            o[j]     = f2b(v[2 * c][j]);
            o[j + 4] = f2b(v[2 * c + 1][j]);
        }
        *(shortx8*)(dst + base + c * 8) = o;
    }
}

// ---------------- 256x256 counted-vmcnt pipelined bf16 GEMM ------------------
// C = A @ W^T, bf16 in/out. BM=BN=256, BK=32, 512 thr = 8 waves (2Mx4N),
// per-wave output 128x64 (acc[8][4] f32x4 = 128 VGPR).
// LDS: 4-deep ring of K-tiles, 4 x (A 16KB + B 16KB) = 128 KiB.
// Pipeline: stage tile t+3 each step, s_waitcnt vmcnt(12) (3 tiles x 4 loads
// in flight) -- never drained to 0 in the main loop (T4). Raw s_barrier (no
// implicit vmcnt(0) drain), sched_barrier(0) fences at phase boundaries,
// setprio(1) around the MFMA cluster (T5).
// LDS swizzle (T2): 16B chunk p = c ^ (row & 3), applied via pre-swizzled
// GLOBAL source (global_load_lds dest must stay linear) + swizzled ds_read.
#define BKS 32
#define NTILES (K_DIM / BKS)   // 64

__global__ __launch_bounds__(512, 2) void gemm256_bf16_kernel(
    const short* __restrict__ A, const short* __restrict__ W, short* __restrict__ C)
{
    __shared__ __align__(16) short lds[4 * 16384];   // 128 KiB

    const int tid  = threadIdx.x;
    const int lane = tid & 63;
    const int wave = tid >> 6;
    const int wr   = wave >> 2;        // 0..1  (M)
    const int wc   = wave & 3;         // 0..3  (N)
    const int blockRow = blockIdx.y * 256;
    const int blockCol = blockIdx.x * 256;

    // staging: linear chunk q (0..1023) -> LDS slot q*16B (row=q>>2, p=q&3);
    // fetch global chunk c = p ^ (row&3)  (involution; 4 lanes cover one 64B
    // row segment in permuted order -> coalescing intact).
    const int q0 = tid, q1 = tid + 512;
    const int sr0 = q0 >> 2, sc0 = (q0 & 3) ^ (sr0 & 3);
    const int sr1 = q1 >> 2, sc1 = (q1 & 3) ^ (sr1 & 3);
    const short* gA0 = A + (size_t)(blockRow + sr0) * K_DIM + sc0 * 8;
    const short* gA1 = A + (size_t)(blockRow + sr1) * K_DIM + sc1 * 8;
    const short* gB0 = W + (size_t)(blockCol + sr0) * K_DIM + sc0 * 8;
    const short* gB1 = W + (size_t)(blockCol + sr1) * K_DIM + sc1 * 8;

    // fragment reads: row = warpBase + i*16 + fr (warpBase, i*16 ≡ 0 mod 4
    // -> row&3 == fr&3), chunk c = lane>>4, physical p = c ^ (fr&3).
    const int fr    = lane & 15;
    const int pbyte = ((lane >> 4) ^ (fr & 3)) * 16;
    const int aBase = (wr * 128 + fr) * 64 + pbyte;   // byte offset, +i*1024
    const int bBase = (wc * 64  + fr) * 64 + pbyte;   // byte offset, +j*1024

    f32x4 acc[8][4] = {};

    auto stageT = [&](int t) {
        short* dA = lds + (t & 3) * 16384;
        short* dB = dA + 8192;
        const int ko = t * BKS;
        __builtin_amdgcn_global_load_lds(
            (const __attribute__((address_space(1))) void*)(gA0 + ko),
            (__attribute__((address_space(3))) void*)(dA + q0 * 8), 16, 0, 0);
        __builtin_amdgcn_global_load_lds(
            (const __attribute__((address_space(1))) void*)(gB0 + ko),
            (__attribute__((address_space(3))) void*)(dB + q0 * 8), 16, 0, 0);
        __builtin_amdgcn_global_load_lds(
            (const __attribute__((address_space(1))) void*)(gA1 + ko),
            (__attribute__((address_space(3))) void*)(dA + q1 * 8), 16, 0, 0);
        __builtin_amdgcn_global_load_lds(
            (const __attribute__((address_space(1))) void*)(gB1 + ko),
            (__attribute__((address_space(3))) void*)(dB + q1 * 8), 16, 0, 0);
    };

    // prologue: tiles 0..2 in flight (12 loads)
    stageT(0); stageT(1); stageT(2);

    for (int t = 0; t < NTILES; ++t) {
        // BAR1: all waves finished reading buf[(t-1)&3] -> safe to overwrite
        __builtin_amdgcn_s_barrier();
        __builtin_amdgcn_sched_barrier(0);
        if (t + 3 < NTILES) {
            stageT(t + 3);                       // into buf[(t-1)&3]
            asm volatile("s_waitcnt vmcnt(12)" ::: "memory");  // tile t landed
        } else if (t + 2 < NTILES) {
            asm volatile("s_waitcnt vmcnt(8)" ::: "memory");
        } else if (t + 1 < NTILES) {
            asm volatile("s_waitcnt vmcnt(4)" ::: "memory");
        } else {
            asm volatile("s_waitcnt vmcnt(0)" ::: "memory");
        }
        // BAR2: every wave's tile-t loads have landed -> reads are safe
        __builtin_amdgcn_s_barrier();
        __builtin_amdgcn_sched_barrier(0);

        const char* bufA = (const char*)lds + (t & 3) * 32768;
        const char* bufB = bufA + 16384;
        bf16x8 af[8], bfv[4];
#pragma unroll
        for (int i = 0; i < 8; ++i)
            af[i] = *(const bf16x8*)(bufA + aBase + i * 1024);
#pragma unroll
        for (int j = 0; j < 4; ++j)
            bfv[j] = *(const bf16x8*)(bufB + bBase + j * 1024);

        __builtin_amdgcn_s_setprio(1);
#pragma unroll
        for (int i = 0; i < 8; ++i)
#pragma unroll
            for (int j = 0; j < 4; ++j)
                acc[i][j] = __builtin_amdgcn_mfma_f32_16x16x32_bf16(
                    af[i], bfv[j], acc[i][j], 0, 0, 0);
        __builtin_amdgcn_s_setprio(0);
    }

    // C/D layout: col=lane&15, row=(lane>>4)*4+reg
    const int er = (lane >> 4) * 4;
    const int ec = lane & 15;
#pragma unroll
    for (int i = 0; i < 8; ++i) {
        const int rr = blockRow + wr * 128 + i * 16 + er;
#pragma unroll
        for (int j = 0; j < 4; ++j) {
            const int cc = blockCol + wc * 64 + j * 16 + ec;
#pragma unroll
            for (int r = 0; r < 4; ++r)
                C[(size_t)(rr + r) * N_DIM + cc] = f2b(acc[i][j][r]);
        }
    }
}

// ------------- GN epilogue: read bf16 y, +bias, groupnorm, silu*mw*silu, fp32 out
__global__ __launch_bounds__(256) void gn_silu_bf16_kernel(
    const short* __restrict__ Y,
    const float* __restrict__ bias,
    const float* __restrict__ gnw,
    const float* __restrict__ gnb,
    const float* __restrict__ mw,
    float* __restrict__ out)
{
    const int lane = threadIdx.x & 63;
    const int wave = threadIdx.x >> 6;
    const unsigned gid = blockIdx.x * 4u + wave;     // 65536 groups
    const unsigned row = gid >> 4;
    const unsigned grp = gid & 15;
    const int col = grp * GSZ + lane * 8;
    const size_t off = (size_t)row * N_DIM + col;

    bf16x8 v = *(const bf16x8*)(Y + off);
    f32x4 b0 = *(const f32x4*)(bias + col);
    f32x4 b1 = *(const f32x4*)(bias + col + 4);

    float y[8];
    float s = 0.f, s2 = 0.f;
#pragma unroll
    for (int j = 0; j < 8; ++j) {
        y[j] = b2f(v[j]) + (j < 4 ? b0[j] : b1[j - 4]);
        s  += y[j];
        s2 += y[j] * y[j];
    }
#pragma unroll
    for (int d = 1; d < 64; d <<= 1) {
        s  += __shfl_xor(s,  d, 64);
        s2 += __shfl_xor(s2, d, 64);
    }
    const float mean = s * (1.0f / GSZ);
    const float var  = s2 * (1.0f / GSZ) - mean * mean;
    const float inv  = rsqrtf(var + EPSV);

    f32x4 w0 = *(const f32x4*)(gnw + col);
    f32x4 w1 = *(const f32x4*)(gnw + col + 4);
    f32x4 g0 = *(const f32x4*)(gnb + col);
    f32x4 g1 = *(const f32x4*)(gnb + col + 4);
    f32x4 m0 = *(const f32x4*)(mw + col);
    f32x4 m1 = *(const f32x4*)(mw + col + 4);

    f32x4 o0, o1;
#pragma unroll
    for (int j = 0; j < 8; ++j) {
        float gwv = j < 4 ? w0[j] : w1[j - 4];
        float gbv = j < 4 ? g0[j] : g1[j - 4];
        float mwv = j < 4 ? m0[j] : m1[j - 4];
        float n  = (y[j] - mean) * inv * gwv + gbv;
        float s1 = n / (1.f + __expf(-n));
        float m  = s1 * mwv;
        float r  = m / (1.f + __expf(-m));
        if (j < 4) o0[j] = r; else o1[j - 4] = r;
    }
    *(f32x4*)(out + off)     = o0;
    *(f32x4*)(out + off + 4) = o1;
}

// ================== fallback path (round-2, known-good) ======================
__global__ __launch_bounds__(256) void gemm_bt_f32_kernel(
    const float* __restrict__ A, const float* __restrict__ W, float* __restrict__ C)
{
    __shared__ __align__(16) short ldsA[128 * 32];
    __shared__ __align__(16) short ldsB[128 * 32];

    const int tid  = threadIdx.x;
    const int lane = tid & 63;
    const int wave = tid >> 6;
    const int blockRow = blockIdx.y * 128;
    const int blockCol = blockIdx.x * 128;
    const int srow = tid >> 1;
    const int scol = (tid & 1) * 16;
    const int wm  = (wave >> 1) * 64;
    const int wn  = (wave & 1) * 64;
    const int fr  = lane & 15;
    const int fko = (lane >> 4) * 8;

    f32x4 acc[4][4] = {};
    const size_t aRowOff = (size_t)(blockRow + srow) * K_DIM;
    const size_t wRowOff = (size_t)(blockCol + srow) * K_DIM;

    for (int k0 = 0; k0 < K_DIM; k0 += 32) {
        f32x4 va0 = *(const f32x4*)(A + aRowOff + k0 + scol);
        f32x4 va1 = *(const f32x4*)(A + aRowOff + k0 + scol + 4);
        f32x4 va2 = *(const f32x4*)(A + aRowOff + k0 + scol + 8);
        f32x4 va3 = *(const f32x4*)(A + aRowOff + k0 + scol + 12);
        f32x4 vb0 = *(const f32x4*)(W + wRowOff + k0 + scol);
        f32x4 vb1 = *(const f32x4*)(W + wRowOff + k0 + scol + 4);
        f32x4 vb2 = *(const f32x4*)(W + wRowOff + k0 + scol + 8);
        f32x4 vb3 = *(const f32x4*)(W + wRowOff + k0 + scol + 12);
        bf16x8 a0, a1, b0, b1;
#pragma unroll
        for (int j = 0; j < 4; ++j) {
            a0[j] = f2b(va0[j]); a0[j + 4] = f2b(va1[j]);
            a1[j] = f2b(va2[j]); a1[j + 4] = f2b(va3[j]);
            b0[j] = f2b(vb0[j]); b0[j + 4] = f2b(vb1[j]);
            b1[j] = f2b(vb2[j]); b1[j + 4] = f2b(vb3[j]);
        }
        *(bf16x8*)(ldsA + srow * 32 + scol)     = a0;
        *(bf16x8*)(ldsA + srow * 32 + scol + 8) = a1;
        *(bf16x8*)(ldsB + srow * 32 + scol)     = b0;
        *(bf16x8*)(ldsB + srow * 32 + scol + 8) = b1;
        __syncthreads();

        bf16x8 af[4], bfv[4];
#pragma unroll
        for (int i = 0; i < 4; ++i) {
            af[i]  = *(const bf16x8*)(ldsA + (wm + i * 16 + fr) * 32 + fko);
            bfv[i] = *(const bf16x8*)(ldsB + (wn + i * 16 + fr) * 32 + fko);
        }
#pragma unroll
        for (int i = 0; i < 4; ++i)
#pragma unroll
            for (int j = 0; j < 4; ++j)
                acc[i][j] = __builtin_amdgcn_mfma_f32_16x16x32_bf16(
                    af[i], bfv[j], acc[i][j], 0, 0, 0);
        __syncthreads();
    }

    const int er = (lane >> 4) * 4;
    const int ec = lane & 15;
#pragma unroll
    for (int i = 0; i < 4; ++i) {
        const int r0 = blockRow + wm + i * 16 + er;
#pragma unroll
        for (int j = 0; j < 4; ++j) {
            const int c0 = blockCol + wn + j * 16 + ec;
#pragma unroll
            for (int r = 0; r < 4; ++r)
                C[(size_t)(r0 + r) * N_DIM + c0] = acc[i][j][r];
        }
    }
}

__global__ __launch_bounds__(256) void gn_silu_f32_kernel(
    float* __restrict__ Y,
    const float* __restrict__ bias,
    const float* __restrict__ gnw,
    const float* __restrict__ gnb,
    const float* __restrict__ mw)
{
    const int lane = threadIdx.x & 63;
    const int wave = threadIdx.x >> 6;
    const unsigned gid = blockIdx.x * 4u + wave;
    const unsigned row = gid >> 4;
    const unsigned grp = gid & 15;
    const int col = grp * GSZ + lane * 8;
    const size_t off = (size_t)row * N_DIM + col;

    f32x4 v0 = *(const f32x4*)(Y + off);
    f32x4 v1 = *(const f32x4*)(Y + off + 4);
    f32x4 b0 = *(const f32x4*)(bias + col);
    f32x4 b1 = *(const f32x4*)(bias + col + 4);

    float y[8];
    float s = 0.f, s2 = 0.f;
#pragma unroll
    for (int j = 0; j < 8; ++j) {
        y[j] = (j < 4 ? v0[j] + b0[j] : v1[j - 4] + b1[j - 4]);
        s += y[j]; s2 += y[j] * y[j];
    }
#pragma unroll
    for (int d = 1; d < 64; d <<= 1) {
        s  += __shfl_xor(s,  d, 64);
        s2 += __shfl_xor(s2, d, 64);
    }
    const float mean = s * (1.0f / GSZ);
    const float var  = s2 * (1.0f / GSZ) - mean * mean;
    const float inv  = rsqrtf(var + EPSV);

    f32x4 w0 = *(const f32x4*)(gnw + col);
    f32x4 w1 = *(const f32x4*)(gnw + col + 4);
    f32x4 g0 = *(const f32x4*)(gnb + col);
    f32x4 g1 = *(const f32x4*)(gnb + col + 4);
    f32x4 m0 = *(const f32x4*)(mw + col);
    f32x4 m1 = *(const f32x4*)(mw + col + 4);

    f32x4 o0, o1;
#pragma unroll
    for (int j = 0; j < 8; ++j) {
        float gwv = j < 4 ? w0[j] : w1[j - 4];
        float gbv = j < 4 ? g0[j] : g1[j - 4];
        float mwv = j < 4 ? m0[j] : m1[j - 4];
        float n  = (y[j] - mean) * inv * gwv + gbv;
        float s1 = n / (1.f + __expf(-n));
        float m  = s1 * mwv;
        float r  = m / (1.f + __expf(-m));
        if (j < 4) o0[j] = r; else o1[j - 4] = r;
    }
    *(f32x4*)(Y + off)     = o0;
    *(f32x4*)(Y + off + 4) = o1;
}

extern "C" void kernel_launch(void* const* d_in, const int* in_sizes, int n_in,
                              void* d_out, int out_size, void* d_ws, size_t ws_size,
                              hipStream_t stream)
{
    const float* x   = (const float*)d_in[0];
    const float* W   = (const float*)d_in[1];
    const float* b   = (const float*)d_in[2];
    const float* gnw = (const float*)d_in[3];
    const float* gnb = (const float*)d_in[4];
    const float* mw  = (const float*)d_in[5];
    float* out = (float*)d_out;

    // ws layout: xb[NX] | Wb[NW] | yb[NY]  (bf16 shorts) = 117,440,512 bytes
    const size_t need = ((size_t)NX + NW + NY) * sizeof(short);
    const int ngroups = M_DIM * NGRP;       // 65536

    if (ws_size >= need) {
        short* xb = (short*)d_ws;
        short* Wb = xb + NX;
        short* yb = Wb + NW;

        convert_kernel<<<(NX + NW) / (256 * 32), 256, 0, stream>>>(x, W, xb);
        dim3 g256(N_DIM / 256, M_DIM / 256);   // 32 x 16 = 512 blocks
        gemm256_bf16_kernel<<<g256, 512, 0, stream>>>(xb, Wb, yb);
        gn_silu_bf16_kernel<<<ngroups / 4, 256, 0, stream>>>(yb, b, gnw, gnb, mw, out);
    } else {
        dim3 ggrid(N_DIM / 128, M_DIM / 128);
        gemm_bt_f32_kernel<<<ggrid, 256, 0, stream>>>(x, W, out);
        gn_silu_f32_kernel<<<ngroups / 4, 256, 0, stream>>>(out, b, gnw, gnb, mw);
    }
}

// Round 2
// 369.775 us; speedup vs baseline: 1.0853x; 1.0314x over previous
//
#include <hip/hip_runtime.h>

#define M_DIM 4096
#define N_DIM 8192
#define K_DIM 2048
#define NGRP 16
#define GSZ 512
#define EPSV 1e-5f

#define NX (M_DIM * K_DIM)            // x elems  = 8388608
#define NW (N_DIM * K_DIM)            // W elems  = 16777216
#define NY ((size_t)M_DIM * N_DIM)    // y elems  = 33554432

typedef __attribute__((ext_vector_type(8))) short bf16x8;
typedef __attribute__((ext_vector_type(4))) float f32x4;
typedef __attribute__((ext_vector_type(8))) short shortx8;

__device__ __forceinline__ float b2f(short u) {
    union { unsigned u32; float f; } c;
    c.u32 = ((unsigned)(unsigned short)u) << 16;
    return c.f;
}

__device__ __forceinline__ short f2b(float f) {
    union { float f; unsigned u; } c; c.f = f;
    unsigned r = (c.u + 0x7fffu + ((c.u >> 16) & 1u)) >> 16;
    return (short)r;
}

// ---------------- fp32 -> bf16 bulk convert (x then W, contiguous dst) -------
__global__ __launch_bounds__(256) void convert_kernel(
    const float* __restrict__ x, const float* __restrict__ W,
    short* __restrict__ dst)
{
    const size_t base = ((size_t)blockIdx.x * 256 + threadIdx.x) * 32;
    const float* src = (base < NX) ? (x + base) : (W + (base - NX));
    f32x4 v[8];
#pragma unroll
    for (int c = 0; c < 8; ++c) v[c] = *(const f32x4*)(src + c * 4);
#pragma unroll
    for (int c = 0; c < 4; ++c) {
        shortx8 o;
#pragma unroll
        for (int j = 0; j < 4; ++j) {
            o[j]     = f2b(v[2 * c][j]);
            o[j + 4] = f2b(v[2 * c + 1][j]);
        }
        *(shortx8*)(dst + base + c * 8) = o;
    }
}

// ---------------- 256x256 counted-vmcnt + reg-double-buffered bf16 GEMM ------
// C = A @ W^T, bf16 in/out. BM=BN=256, BK=32, 512 thr = 8 waves (2Mx4N),
// per-wave output 128x64 (acc[8][4] f32x4, AGPR).
// LDS: 4-deep ring of K-tiles, 4 x (A 16KB + B 16KB) = 128 KiB.
// Two-level pipeline:
//   - global->LDS: counted vmcnt (T4), 2-3 tiles in flight, never drained to 0
//     in steady state.
//   - LDS->reg: fragment ping-pong (fE/fO). ds_reads for tile t+1 are issued
//     BEFORE the MFMA cluster of tile t; lgkmcnt(12) (= the 12 next-tile reads
//     stay outstanding) retires tile-t reads BEFORE barrier B2, which is what
//     makes re-staging that ring slot safe AND lets MFMAs run on ready regs.
// LDS swizzle (T2, round-0-proven): physical chunk p = c ^ ((row>>1)&3),
// applied via pre-swizzled GLOBAL source (LDS dest of global_load_lds must
// stay linear, m104) + swizzled ds_read chunk. Quarter-wave (16 lanes, fixed
// c) hits all 8 (parity,chunk) slots exactly 2x -> free 2-way.
#define BKS 32
#define NTILES (K_DIM / BKS)   // 64

__global__ __launch_bounds__(512, 2) void gemm256_bf16_kernel(
    const short* __restrict__ A, const short* __restrict__ W, short* __restrict__ C)
{
    __shared__ __align__(16) short lds[4 * 16384];   // 128 KiB

    const int tid  = threadIdx.x;
    const int lane = tid & 63;
    const int wave = tid >> 6;
    const int wr   = wave >> 2;        // 0..1  (M)
    const int wc   = wave & 3;         // 0..3  (N)
    const int blockRow = blockIdx.y * 256;
    const int blockCol = blockIdx.x * 256;

    // staging: linear chunk q (0..1023) -> LDS slot q*16B (row=q>>2, p=q&3);
    // fetch global chunk c = p ^ ((row>>1)&3) = (q&3) ^ ((q>>3)&3).
    // Groups of 8 lanes still cover two full 64B row segments -> coalesced.
    const int q0 = tid, q1 = tid + 512;
    const int sr0 = q0 >> 2, sc0 = (q0 & 3) ^ ((q0 >> 3) & 3);
    const int sr1 = q1 >> 2, sc1 = (q1 & 3) ^ ((q1 >> 3) & 3);
    const int offA0 = (blockRow + sr0) * K_DIM + sc0 * 8;
    const int offA1 = (blockRow + sr1) * K_DIM + sc1 * 8;
    const int offB0 = (blockCol + sr0) * K_DIM + sc0 * 8;
    const int offB1 = (blockCol + sr1) * K_DIM + sc1 * 8;

    // fragment reads: row = warpBase + i*16 + fr (bases are multiples of 16,
    // so (row>>1)&3 == (fr>>1)&3), logical chunk c = lane>>4,
    // physical p = c ^ ((fr>>1)&3).
    const int fr    = lane & 15;
    const int pbyte = ((lane >> 4) ^ ((fr >> 1) & 3)) * 16;
    const int aBase = (wr * 128 + fr) * 64 + pbyte;   // byte offset, +i*1024
    const int bBase = (wc * 64  + fr) * 64 + pbyte;   // byte offset, +j*1024

    f32x4 acc[8][4] = {};

    auto stageT = [&](int t) {
        short* dA = lds + (t & 3) * 16384;
        short* dB = dA + 8192;
        const int ko = t * BKS;
        __builtin_amdgcn_global_load_lds(
            (const __attribute__((address_space(1))) void*)(A + offA0 + ko),
            (__attribute__((address_space(3))) void*)(dA + q0 * 8), 16, 0, 0);
        __builtin_amdgcn_global_load_lds(
            (const __attribute__((address_space(1))) void*)(W + offB0 + ko),
            (__attribute__((address_space(3))) void*)(dB + q0 * 8), 16, 0, 0);
        __builtin_amdgcn_global_load_lds(
            (const __attribute__((address_space(1))) void*)(A + offA1 + ko),
            (__attribute__((address_space(3))) void*)(dA + q1 * 8), 16, 0, 0);
        __builtin_amdgcn_global_load_lds(
            (const __attribute__((address_space(1))) void*)(W + offB1 + ko),
            (__attribute__((address_space(3))) void*)(dB + q1 * 8), 16, 0, 0);
    };

    auto ldfrags = [&](int t, bf16x8 (&f)[12]) {
        const char* bufA = (const char*)lds + (t & 3) * 32768;
        const char* bufB = bufA + 16384;
#pragma unroll
        for (int i = 0; i < 8; ++i)
            f[i] = *(const bf16x8*)(bufA + aBase + i * 1024);
#pragma unroll
        for (int j = 0; j < 4; ++j)
            f[8 + j] = *(const bf16x8*)(bufB + bBase + j * 1024);
    };

    auto domfma = [&](bf16x8 (&f)[12]) {
        __builtin_amdgcn_s_setprio(1);
#pragma unroll
        for (int i = 0; i < 8; ++i)
#pragma unroll
            for (int j = 0; j < 4; ++j)
                acc[i][j] = __builtin_amdgcn_mfma_f32_16x16x32_bf16(
                    f[i], f[8 + j], acc[i][j], 0, 0, 0);
        __builtin_amdgcn_s_setprio(0);
    };

    auto step = [&](int t, bf16x8 (&cur)[12], bf16x8 (&nxt)[12]) {
        // stage 3 ahead; wait so tile t+1 is landed (counted, never 0 until tail)
        if (t + 3 < NTILES) {
            stageT(t + 3);                       // into buf[(t-1)&3]
            asm volatile("s_waitcnt vmcnt(8)" ::: "memory");
        } else if (t + 2 < NTILES) {
            asm volatile("s_waitcnt vmcnt(4)" ::: "memory");
        } else if (t + 1 < NTILES) {
            asm volatile("s_waitcnt vmcnt(0)" ::: "memory");
        }
        __builtin_amdgcn_s_barrier();            // B1: tile t+1 visible block-wide
        __builtin_amdgcn_sched_barrier(0);
        if (t + 1 < NTILES) {
            ldfrags(t + 1, nxt);                 // issue; no drain
            asm volatile("s_waitcnt lgkmcnt(12)" ::: "memory");  // tile-t frags ready
        } else {
            asm volatile("s_waitcnt lgkmcnt(0)" ::: "memory");
        }
        __builtin_amdgcn_sched_barrier(0);
        __builtin_amdgcn_s_barrier();            // B2: all waves' tile-t reads retired
        __builtin_amdgcn_sched_barrier(0);
        domfma(cur);                             // regs ready; LDS of t+1 in flight
    };

    bf16x8 fE[12], fO[12];

    // prologue: tiles 0..2 in flight (12 loads); land tile 0; preload frags(0)
    stageT(0); stageT(1); stageT(2);
    asm volatile("s_waitcnt vmcnt(8)" ::: "memory");
    __builtin_amdgcn_s_barrier();
    __builtin_amdgcn_sched_barrier(0);
    ldfrags(0, fE);

    for (int t = 0; t < NTILES; t += 2) {        // NTILES even
        step(t,     fE, fO);
        step(t + 1, fO, fE);
    }

    // C/D layout: col=lane&15, row=(lane>>4)*4+reg
    const int er = (lane >> 4) * 4;
    const int ec = lane & 15;
#pragma unroll
    for (int i = 0; i < 8; ++i) {
        const int rr = blockRow + wr * 128 + i * 16 + er;
#pragma unroll
        for (int j = 0; j < 4; ++j) {
            const int cc = blockCol + wc * 64 + j * 16 + ec;
#pragma unroll
            for (int r = 0; r < 4; ++r)
                C[(size_t)(rr + r) * N_DIM + cc] = f2b(acc[i][j][r]);
        }
    }
}

// ------------- GN epilogue: read bf16 y, +bias, groupnorm, silu*mw*silu, fp32 out
__global__ __launch_bounds__(256) void gn_silu_bf16_kernel(
    const short* __restrict__ Y,
    const float* __restrict__ bias,
    const float* __restrict__ gnw,
    const float* __restrict__ gnb,
    const float* __restrict__ mw,
    float* __restrict__ out)
{
    const int lane = threadIdx.x & 63;
    const int wave = threadIdx.x >> 6;
    const unsigned gid = blockIdx.x * 4u + wave;     // 65536 groups
    const unsigned row = gid >> 4;
    const unsigned grp = gid & 15;
    const int col = grp * GSZ + lane * 8;
    const size_t off = (size_t)row * N_DIM + col;

    bf16x8 v = *(const bf16x8*)(Y + off);
    f32x4 b0 = *(const f32x4*)(bias + col);
    f32x4 b1 = *(const f32x4*)(bias + col + 4);

    float y[8];
    float s = 0.f, s2 = 0.f;
#pragma unroll
    for (int j = 0; j < 8; ++j) {
        y[j] = b2f(v[j]) + (j < 4 ? b0[j] : b1[j - 4]);
        s  += y[j];
        s2 += y[j] * y[j];
    }
#pragma unroll
    for (int d = 1; d < 64; d <<= 1) {
        s  += __shfl_xor(s,  d, 64);
        s2 += __shfl_xor(s2, d, 64);
    }
    const float mean = s * (1.0f / GSZ);
    const float var  = s2 * (1.0f / GSZ) - mean * mean;
    const float inv  = rsqrtf(var + EPSV);

    f32x4 w0 = *(const f32x4*)(gnw + col);
    f32x4 w1 = *(const f32x4*)(gnw + col + 4);
    f32x4 g0 = *(const f32x4*)(gnb + col);
    f32x4 g1 = *(const f32x4*)(gnb + col + 4);
    f32x4 m0 = *(const f32x4*)(mw + col);
    f32x4 m1 = *(const f32x4*)(mw + col + 4);

    f32x4 o0, o1;
#pragma unroll
    for (int j = 0; j < 8; ++j) {
        float gwv = j < 4 ? w0[j] : w1[j - 4];
        float gbv = j < 4 ? g0[j] : g1[j - 4];
        float mwv = j < 4 ? m0[j] : m1[j - 4];
        float n  = (y[j] - mean) * inv * gwv + gbv;
        float s1 = n / (1.f + __expf(-n));
        float m  = s1 * mwv;
        float r  = m / (1.f + __expf(-m));
        if (j < 4) o0[j] = r; else o1[j - 4] = r;
    }
    *(f32x4*)(out + off)     = o0;
    *(f32x4*)(out + off + 4) = o1;
}

// ================== fallback path (round-2, known-good) ======================
__global__ __launch_bounds__(256) void gemm_bt_f32_kernel(
    const float* __restrict__ A, const float* __restrict__ W, float* __restrict__ C)
{
    __shared__ __align__(16) short ldsA[128 * 32];
    __shared__ __align__(16) short ldsB[128 * 32];

    const int tid  = threadIdx.x;
    const int lane = tid & 63;
    const int wave = tid >> 6;
    const int blockRow = blockIdx.y * 128;
    const int blockCol = blockIdx.x * 128;
    const int srow = tid >> 1;
    const int scol = (tid & 1) * 16;
    const int wm  = (wave >> 1) * 64;
    const int wn  = (wave & 1) * 64;
    const int fr  = lane & 15;
    const int fko = (lane >> 4) * 8;

    f32x4 acc[4][4] = {};
    const size_t aRowOff = (size_t)(blockRow + srow) * K_DIM;
    const size_t wRowOff = (size_t)(blockCol + srow) * K_DIM;

    for (int k0 = 0; k0 < K_DIM; k0 += 32) {
        f32x4 va0 = *(const f32x4*)(A + aRowOff + k0 + scol);
        f32x4 va1 = *(const f32x4*)(A + aRowOff + k0 + scol + 4);
        f32x4 va2 = *(const f32x4*)(A + aRowOff + k0 + scol + 8);
        f32x4 va3 = *(const f32x4*)(A + aRowOff + k0 + scol + 12);
        f32x4 vb0 = *(const f32x4*)(W + wRowOff + k0 + scol);
        f32x4 vb1 = *(const f32x4*)(W + wRowOff + k0 + scol + 4);
        f32x4 vb2 = *(const f32x4*)(W + wRowOff + k0 + scol + 8);
        f32x4 vb3 = *(const f32x4*)(W + wRowOff + k0 + scol + 12);
        bf16x8 a0, a1, b0, b1;
#pragma unroll
        for (int j = 0; j < 4; ++j) {
            a0[j] = f2b(va0[j]); a0[j + 4] = f2b(va1[j]);
            a1[j] = f2b(va2[j]); a1[j + 4] = f2b(va3[j]);
            b0[j] = f2b(vb0[j]); b0[j + 4] = f2b(vb1[j]);
            b1[j] = f2b(vb2[j]); b1[j + 4] = f2b(vb3[j]);
        }
        *(bf16x8*)(ldsA + srow * 32 + scol)     = a0;
        *(bf16x8*)(ldsA + srow * 32 + scol + 8) = a1;
        *(bf16x8*)(ldsB + srow * 32 + scol)     = b0;
        *(bf16x8*)(ldsB + srow * 32 + scol + 8) = b1;
        __syncthreads();

        bf16x8 af[4], bfv[4];
#pragma unroll
        for (int i = 0; i < 4; ++i) {
            af[i]  = *(const bf16x8*)(ldsA + (wm + i * 16 + fr) * 32 + fko);
            bfv[i] = *(const bf16x8*)(ldsB + (wn + i * 16 + fr) * 32 + fko);
        }
#pragma unroll
        for (int i = 0; i < 4; ++i)
#pragma unroll
            for (int j = 0; j < 4; ++j)
                acc[i][j] = __builtin_amdgcn_mfma_f32_16x16x32_bf16(
                    af[i], bfv[j], acc[i][j], 0, 0, 0);
        __syncthreads();
    }

    const int er = (lane >> 4) * 4;
    const int ec = lane & 15;
#pragma unroll
    for (int i = 0; i < 4; ++i) {
        const int r0 = blockRow + wm + i * 16 + er;
#pragma unroll
        for (int j = 0; j < 4; ++j) {
            const int c0 = blockCol + wn + j * 16 + ec;
#pragma unroll
            for (int r = 0; r < 4; ++r)
                C[(size_t)(r0 + r) * N_DIM + c0] = acc[i][j][r];
        }
    }
}

__global__ __launch_bounds__(256) void gn_silu_f32_kernel(
    float* __restrict__ Y,
    const float* __restrict__ bias,
    const float* __restrict__ gnw,
    const float* __restrict__ gnb,
    const float* __restrict__ mw)
{
    const int lane = threadIdx.x & 63;
    const int wave = threadIdx.x >> 6;
    const unsigned gid = blockIdx.x * 4u + wave;
    const unsigned row = gid >> 4;
    const unsigned grp = gid & 15;
    const int col = grp * GSZ + lane * 8;
    const size_t off = (size_t)row * N_DIM + col;

    f32x4 v0 = *(const f32x4*)(Y + off);
    f32x4 v1 = *(const f32x4*)(Y + off + 4);
    f32x4 b0 = *(const f32x4*)(bias + col);
    f32x4 b1 = *(const f32x4*)(bias + col + 4);

    float y[8];
    float s = 0.f, s2 = 0.f;
#pragma unroll
    for (int j = 0; j < 8; ++j) {
        y[j] = (j < 4 ? v0[j] + b0[j] : v1[j - 4] + b1[j - 4]);
        s += y[j]; s2 += y[j] * y[j];
    }
#pragma unroll
    for (int d = 1; d < 64; d <<= 1) {
        s  += __shfl_xor(s,  d, 64);
        s2 += __shfl_xor(s2, d, 64);
    }
    const float mean = s * (1.0f / GSZ);
    const float var  = s2 * (1.0f / GSZ) - mean * mean;
    const float inv  = rsqrtf(var + EPSV);

    f32x4 w0 = *(const f32x4*)(gnw + col);
    f32x4 w1 = *(const f32x4*)(gnw + col + 4);
    f32x4 g0 = *(const f32x4*)(gnb + col);
    f32x4 g1 = *(const f32x4*)(gnb + col + 4);
    f32x4 m0 = *(const f32x4*)(mw + col);
    f32x4 m1 = *(const f32x4*)(mw + col + 4);

    f32x4 o0, o1;
#pragma unroll
    for (int j = 0; j < 8; ++j) {
        float gwv = j < 4 ? w0[j] : w1[j - 4];
        float gbv = j < 4 ? g0[j] : g1[j - 4];
        float mwv = j < 4 ? m0[j] : m1[j - 4];
        float n  = (y[j] - mean) * inv * gwv + gbv;
        float s1 = n / (1.f + __expf(-n));
        float m  = s1 * mwv;
        float r  = m / (1.f + __expf(-m));
        if (j < 4) o0[j] = r; else o1[j - 4] = r;
    }
    *(f32x4*)(Y + off)     = o0;
    *(f32x4*)(Y + off + 4) = o1;
}

extern "C" void kernel_launch(void* const* d_in, const int* in_sizes, int n_in,
                              void* d_out, int out_size, void* d_ws, size_t ws_size,
                              hipStream_t stream)
{
    const float* x   = (const float*)d_in[0];
    const float* W   = (const float*)d_in[1];
    const float* b   = (const float*)d_in[2];
    const float* gnw = (const float*)d_in[3];
    const float* gnb = (const float*)d_in[4];
    const float* mw  = (const float*)d_in[5];
    float* out = (float*)d_out;

    // ws layout: xb[NX] | Wb[NW] | yb[NY]  (bf16 shorts) = 117,440,512 bytes
    const size_t need = ((size_t)NX + NW + NY) * sizeof(short);
    const int ngroups = M_DIM * NGRP;       // 65536

    if (ws_size >= need) {
        short* xb = (short*)d_ws;
        short* Wb = xb + NX;
        short* yb = Wb + NW;

        convert_kernel<<<(NX + NW) / (256 * 32), 256, 0, stream>>>(x, W, xb);
        dim3 g256(N_DIM / 256, M_DIM / 256);   // 32 x 16 = 512 blocks
        gemm256_bf16_kernel<<<g256, 512, 0, stream>>>(xb, Wb, yb);
        gn_silu_bf16_kernel<<<ngroups / 4, 256, 0, stream>>>(yb, b, gnw, gnb, mw, out);
    } else {
        dim3 ggrid(N_DIM / 128, M_DIM / 128);
        gemm_bt_f32_kernel<<<ggrid, 256, 0, stream>>>(x, W, out);
        gn_silu_f32_kernel<<<ngroups / 4, 256, 0, stream>>>(out, b, gnw, gnb, mw);
    }
}